// Round 2
// baseline (607.897 us; speedup 1.0000x reference)
//
#include <hip/hip_runtime.h>

// Problem: y[b,l,o] = sum_{k,i} x[b, idx[l,k], i] * mask[k,i,o] + bias[o]
// B=4, L=10000, K=16, I=256, O=256  => gathered GEMM M=40000, N=256, KK=4096
#define Bdim 4
#define Ldim 10000
#define Kdim 16
#define Idim 256
#define Odim 256

typedef __attribute__((ext_vector_type(8))) __bf16 bf16x8;
typedef __attribute__((ext_vector_type(4))) float f32x4;

// ---------------- pre-pass 1: x fp32 -> bf16 ----------------
__global__ __launch_bounds__(256)
void convert_x(const float* __restrict__ x, __bf16* __restrict__ xb)
{
    const size_t base = ((size_t)blockIdx.x * 256 + threadIdx.x) * 16;
#pragma unroll
    for (int j = 0; j < 2; ++j) {
        const float4 f0 = *(const float4*)(x + base + j * 8);
        const float4 f1 = *(const float4*)(x + base + j * 8 + 4);
        bf16x8 v;
        v[0] = (__bf16)f0.x; v[1] = (__bf16)f0.y; v[2] = (__bf16)f0.z; v[3] = (__bf16)f0.w;
        v[4] = (__bf16)f1.x; v[5] = (__bf16)f1.y; v[6] = (__bf16)f1.z; v[7] = (__bf16)f1.w;
        *(bf16x8*)(xb + base + j * 8) = v;
    }
}

// ---------------- pre-pass 2: mask [kk=4096][o=256] fp32 -> Wt [o=256][kk=4096] bf16 ----------------
__global__ __launch_bounds__(256)
void convert_mask(const float* __restrict__ mask, __bf16* __restrict__ wt)
{
    __shared__ float lds[32][33];
    const int t  = threadIdx.x;
    const int r  = t >> 5;      // 0..7
    const int c  = t & 31;
    const int kk0 = blockIdx.x * 32;
    const int o0  = blockIdx.y * 32;
#pragma unroll
    for (int rr = r; rr < 32; rr += 8)
        lds[rr][c] = mask[(size_t)(kk0 + rr) * Odim + o0 + c];
    __syncthreads();
#pragma unroll
    for (int rr = r; rr < 32; rr += 8)
        wt[(size_t)(o0 + rr) * (Kdim * Idim) + kk0 + c] = (__bf16)lds[c][rr];
}

// ---------------- main GEMM: bf16 gathered A x Wt, fp32 acc ----------------
#define TL 32          // l per block
#define BM 128         // = Bdim * TL
#define BN 256         // full O per block (dedups the gather)
#define LDA 72         // LDS row stride in bf16 (64 + 8 pad)

__global__ __launch_bounds__(256)
void piconv_gemm(const __bf16* __restrict__ xb,
                 const int* __restrict__ idxT,
                 const __bf16* __restrict__ wt,
                 const float* __restrict__ bias,
                 float* __restrict__ out)
{
    __shared__ __bf16 Alds[BM * LDA];   // 18 KB
    __shared__ __bf16 Wlds[BN * LDA];   // 36 KB

    const int t  = threadIdx.x;
    const int l0 = blockIdx.x * TL;

    const int lane = t & 63;
    const int wid  = t >> 6;          // 4 waves, 2x2; wave tile 64(m) x 128(n)
    const int wm   = wid >> 1;
    const int wn   = wid & 1;
    const int q    = lane >> 4;
    const int r16  = lane & 15;

    f32x4 acc[4][8] = {};

    // A staging: 2 threads per row
    const int am    = t >> 1;         // row 0..127
    const int ahalf = t & 1;
    const int alt   = am & 31;
    const int abb   = am >> 5;
    const int al    = l0 + alt;
    const bool avalid = (al < Ldim);

    for (int kb = 0; kb < 64; ++kb) {
        // ---- stage A (gathered, bf16) ----
        {
            const int k  = kb >> 2;
            const int i0 = ((kb & 3) << 6) + (ahalf << 5);
            const int iv = avalid ? idxT[al * Kdim + k] : 0;
            const __bf16* src = xb + (((size_t)(abb * Ldim + iv)) << 8) + i0;
#pragma unroll
            for (int j = 0; j < 4; ++j)
                *(bf16x8*)&Alds[am * LDA + (ahalf << 5) + j * 8] = *(const bf16x8*)(src + j * 8);
        }
        // ---- stage W (pre-transposed bf16, contiguous 16B chunks) ----
        {
#pragma unroll
            for (int it = 0; it < 8; ++it) {
                const int c = t + it * 256;       // 0..2047
                const int n = c >> 3;
                const int g = c & 7;
                *(bf16x8*)&Wlds[n * LDA + g * 8] =
                    *(const bf16x8*)(wt + ((size_t)n << 12) + kb * 64 + g * 8);
            }
        }
        __syncthreads();
        // ---- compute: 2 k-steps of 16x16x32, 4x8 per wave ----
#pragma unroll
        for (int ks = 0; ks < 2; ++ks) {
            bf16x8 af[4], bfr[8];
#pragma unroll
            for (int mi = 0; mi < 4; ++mi)
                af[mi] = *(bf16x8*)&Alds[(wm * 64 + mi * 16 + r16) * LDA + ks * 32 + q * 8];
#pragma unroll
            for (int ni = 0; ni < 8; ++ni)
                bfr[ni] = *(bf16x8*)&Wlds[(wn * 128 + ni * 16 + r16) * LDA + ks * 32 + q * 8];
#pragma unroll
            for (int mi = 0; mi < 4; ++mi)
#pragma unroll
                for (int ni = 0; ni < 8; ++ni)
                    acc[mi][ni] = __builtin_amdgcn_mfma_f32_16x16x32_bf16(
                        af[mi], bfr[ni], acc[mi][ni], 0, 0, 0);
        }
        __syncthreads();
    }

    // ---- epilogue: C/D layout col=lane&15, row=(lane>>4)*4+reg ----
    float bv[8];
#pragma unroll
    for (int ni = 0; ni < 8; ++ni)
        bv[ni] = bias[wn * 128 + ni * 16 + r16];
#pragma unroll
    for (int mi = 0; mi < 4; ++mi) {
        const int mrow = wm * 64 + mi * 16 + q * 4;
#pragma unroll
        for (int rr = 0; rr < 4; ++rr) {
            const int m  = mrow + rr;
            const int lt = m & 31;
            const int bb = m >> 5;
            const int l  = l0 + lt;
            if (l < Ldim) {
                float* dst = out + (((size_t)(bb * Ldim + l)) << 8) + wn * 128 + r16;
#pragma unroll
                for (int ni = 0; ni < 8; ++ni)
                    dst[ni * 16] = acc[mi][ni][rr] + bv[ni];
            }
        }
    }
}

// ---------------- fallback (round-1 kernel, fp32 inputs, no ws) ----------------
#define FTL 32
#define FBN 128
#define FLDA 72
__global__ __launch_bounds__(256)
void piconv_fallback(const float* __restrict__ x,
                     const int* __restrict__ idxT,
                     const float* __restrict__ mask,
                     const float* __restrict__ bias,
                     float* __restrict__ out)
{
    __shared__ __bf16 Alds[128 * FLDA];
    __shared__ __bf16 Wlds[FBN * FLDA];
    const int t  = threadIdx.x;
    const int l0 = blockIdx.x * FTL;
    const int n0 = blockIdx.y * FBN;
    const int lane = t & 63;
    const int wid  = t >> 6;
    const int wm   = wid >> 1;
    const int wn   = wid & 1;
    const int q    = lane >> 4;
    const int r16  = lane & 15;
    f32x4 acc[4][4] = {};
    const int am    = t >> 1;
    const int ahalf = t & 1;
    const int alt   = am & 31;
    const int abb   = am >> 5;
    const int al    = l0 + alt;
    const bool avalid = (al < Ldim);
    for (int kb = 0; kb < 64; ++kb) {
        {
            const int ksl = kb >> 2;
            const int i0  = ((kb & 3) << 6) + (ahalf << 5);
            const int idx = avalid ? idxT[al * Kdim + ksl] : 0;
            const float* src = x + (((size_t)(abb * Ldim + idx)) << 8) + i0;
#pragma unroll
            for (int j = 0; j < 4; ++j) {
                const float4 f0 = *(const float4*)(src + j * 8);
                const float4 f1 = *(const float4*)(src + j * 8 + 4);
                bf16x8 v;
                v[0] = (__bf16)f0.x; v[1] = (__bf16)f0.y; v[2] = (__bf16)f0.z; v[3] = (__bf16)f0.w;
                v[4] = (__bf16)f1.x; v[5] = (__bf16)f1.y; v[6] = (__bf16)f1.z; v[7] = (__bf16)f1.w;
                *(bf16x8*)&Alds[am * FLDA + (ahalf << 5) + j * 8] = v;
            }
        }
        {
#pragma unroll
            for (int it = 0; it < 4; ++it) {
                const int pair = t + it * 256;
                const int n    = pair & 127;
                const int g    = pair >> 7;
                const float* src = mask + (((size_t)(kb * 64 + g * 8)) << 8) + n0 + n;
                bf16x8 v;
#pragma unroll
                for (int j = 0; j < 8; ++j)
                    v[j] = (__bf16)src[(size_t)j << 8];
                *(bf16x8*)&Wlds[n * FLDA + g * 8] = v;
            }
        }
        __syncthreads();
#pragma unroll
        for (int ks = 0; ks < 2; ++ks) {
            bf16x8 af[4], bfr[4];
#pragma unroll
            for (int mi = 0; mi < 4; ++mi)
                af[mi] = *(bf16x8*)&Alds[(wm * 64 + mi * 16 + r16) * FLDA + ks * 32 + q * 8];
#pragma unroll
            for (int ni = 0; ni < 4; ++ni)
                bfr[ni] = *(bf16x8*)&Wlds[(wn * 64 + ni * 16 + r16) * FLDA + ks * 32 + q * 8];
#pragma unroll
            for (int mi = 0; mi < 4; ++mi)
#pragma unroll
                for (int ni = 0; ni < 4; ++ni)
                    acc[mi][ni] = __builtin_amdgcn_mfma_f32_16x16x32_bf16(
                        af[mi], bfr[ni], acc[mi][ni], 0, 0, 0);
        }
        __syncthreads();
    }
    float bv[4];
#pragma unroll
    for (int ni = 0; ni < 4; ++ni)
        bv[ni] = bias[n0 + wn * 64 + ni * 16 + r16];
#pragma unroll
    for (int mi = 0; mi < 4; ++mi) {
        const int mrow = wm * 64 + mi * 16 + q * 4;
#pragma unroll
        for (int rr = 0; rr < 4; ++rr) {
            const int m  = mrow + rr;
            const int lt = m & 31;
            const int bb = m >> 5;
            const int l  = l0 + lt;
            if (l < Ldim) {
                float* dst = out + (((size_t)(bb * Ldim + l)) << 8) + n0 + wn * 64 + r16;
#pragma unroll
                for (int ni = 0; ni < 4; ++ni)
                    dst[ni * 16] = acc[mi][ni][rr] + bv[ni];
            }
        }
    }
}

extern "C" void kernel_launch(void* const* d_in, const int* in_sizes, int n_in,
                              void* d_out, int out_size, void* d_ws, size_t ws_size,
                              hipStream_t stream) {
    const float* x    = (const float*)d_in[0];
    const int*   idx  = (const int*)d_in[1];
    const float* mask = (const float*)d_in[2];
    const float* bias = (const float*)d_in[3];
    float* out = (float*)d_out;

    const size_t xb_bytes = (size_t)Bdim * Ldim * Idim * 2;          // 20,480,000
    const size_t wt_bytes = (size_t)Kdim * Idim * Odim * 2;          //  2,097,152

    if (ws_size >= xb_bytes + wt_bytes) {
        __bf16* xb = (__bf16*)d_ws;
        __bf16* wt = (__bf16*)((char*)d_ws + xb_bytes);
        convert_x<<<(Bdim * Ldim * Idim) / (256 * 16), 256, 0, stream>>>(x, xb);
        convert_mask<<<dim3((Kdim * Idim) / 32, Odim / 32), 256, 0, stream>>>(mask, wt);
        piconv_gemm<<<(Ldim + TL - 1) / TL, 256, 0, stream>>>(xb, idx, wt, bias, out);
    } else {
        dim3 grid((Ldim + FTL - 1) / FTL, Odim / FBN, 1);
        piconv_fallback<<<grid, 256, 0, stream>>>(x, idx, mask, bias, out);
    }
}

// Round 3
// 219.110 us; speedup vs baseline: 2.7744x; 2.7744x over previous
//
#include <hip/hip_runtime.h>

// Problem: y[b,l,o] = sum_{k,i} x[b, idx[l,k], i] * mask[k,i,o] + bias[o]
// B=4, L=10000, K=16, I=256, O=256  => gathered GEMM M=40000, N=256, KK=4096
#define Bdim 4
#define Ldim 10000
#define Kdim 16
#define Idim 256
#define Odim 256

typedef __attribute__((ext_vector_type(8))) __bf16 bf16x8;
typedef __attribute__((ext_vector_type(4))) float f32x4;

// ---------------- pre-pass 1: x fp32 -> bf16 ----------------
__global__ __launch_bounds__(256)
void convert_x(const float* __restrict__ x, __bf16* __restrict__ xb)
{
    const size_t base = ((size_t)blockIdx.x * 256 + threadIdx.x) * 16;
#pragma unroll
    for (int j = 0; j < 2; ++j) {
        const float4 f0 = *(const float4*)(x + base + j * 8);
        const float4 f1 = *(const float4*)(x + base + j * 8 + 4);
        bf16x8 v;
        v[0] = (__bf16)f0.x; v[1] = (__bf16)f0.y; v[2] = (__bf16)f0.z; v[3] = (__bf16)f0.w;
        v[4] = (__bf16)f1.x; v[5] = (__bf16)f1.y; v[6] = (__bf16)f1.z; v[7] = (__bf16)f1.w;
        *(bf16x8*)(xb + base + j * 8) = v;
    }
}

// ---------------- pre-pass 2: mask [kk][o] fp32 -> Wt [o][kk] bf16 ----------------
__global__ __launch_bounds__(256)
void convert_mask(const float* __restrict__ mask, __bf16* __restrict__ wt)
{
    __shared__ float lds[32][33];
    const int t  = threadIdx.x;
    const int r  = t >> 5;
    const int c  = t & 31;
    const int kk0 = blockIdx.x * 32;
    const int o0  = blockIdx.y * 32;
#pragma unroll
    for (int rr = r; rr < 32; rr += 8)
        lds[rr][c] = mask[(size_t)(kk0 + rr) * Odim + o0 + c];
    __syncthreads();
#pragma unroll
    for (int rr = r; rr < 32; rr += 8)
        wt[(size_t)(o0 + rr) * (Kdim * Idim) + kk0 + c] = (__bf16)lds[c][rr];
}

// ---------------- main GEMM ----------------
#define TL 16          // l per block -> 625 blocks
#define BM 64          // = Bdim * TL
#define BN 256
#define LDA 72         // LDS row stride in bf16 (64 + 8 pad)

__global__ __launch_bounds__(256, 3)
void piconv_gemm(const __bf16* __restrict__ xb,
                 const int* __restrict__ idxT,
                 const __bf16* __restrict__ wt,
                 const float* __restrict__ bias,
                 float* __restrict__ out)
{
    __shared__ __bf16 Alds[BM * LDA];     // 9.2 KB
    __shared__ __bf16 Wlds[BN * LDA];     // 36.9 KB
    __shared__ int    idx_lds[TL][Kdim];  // 1 KB

    const int t  = threadIdx.x;
    const int l0 = blockIdx.x * TL;       // exact: 625*16 = 10000

    const int lane = t & 63;
    const int wid  = t >> 6;              // wave n-quadrant: n in [wid*64, wid*64+64)
    const int q    = lane >> 4;
    const int r16  = lane & 15;

    // stage idx table once
    {
        const int lt = t >> 4, k = t & 15;
        idx_lds[lt][k] = idxT[(l0 + lt) * Kdim + k];
    }

    // A staging: 4 threads per row, 32 B each
    const int arow  = t >> 2;             // 0..63  (m-row: bb = arow>>4, lt = arow&15)
    const int apart = t & 3;
    const int alt   = arow & 15;
    const int abb   = arow >> 4;
    const size_t abase = ((size_t)abb * Ldim) << 8;

    // W staging: per thread 8 chunks of 16 B
    const __bf16* wp = wt + (((size_t)(t >> 3)) << 12) + (t & 7) * 8;

    f32x4 acc[4][4] = {};
    bf16x8 aN[2], wN[8];

    __syncthreads();   // idx table ready

    // prologue: load kb=0
    {
        const int iv = idx_lds[alt][0];
        const __bf16* src = xb + abase + (((size_t)iv) << 8) + apart * 16;
        aN[0] = *(const bf16x8*)src;
        aN[1] = *(const bf16x8*)(src + 8);
#pragma unroll
        for (int it = 0; it < 8; ++it)
            wN[it] = *(const bf16x8*)(wp + ((size_t)it << 17));
    }

    for (int kb = 0; kb < 64; ++kb) {
        // ---- store staged regs to LDS ----
        *(bf16x8*)&Alds[arow * LDA + apart * 16]     = aN[0];
        *(bf16x8*)&Alds[arow * LDA + apart * 16 + 8] = aN[1];
#pragma unroll
        for (int it = 0; it < 8; ++it)
            *(bf16x8*)&Wlds[(it * 32 + (t >> 3)) * LDA + (t & 7) * 8] = wN[it];
        __syncthreads();

        // ---- prefetch kb+1 (overlaps compute below) ----
        if (kb < 63) {
            const int kn = (kb + 1) >> 2;
            const int io = (((kb + 1) & 3) << 6) + apart * 16;
            const int iv = idx_lds[alt][kn];
            const __bf16* src = xb + abase + (((size_t)iv) << 8) + io;
            aN[0] = *(const bf16x8*)src;
            aN[1] = *(const bf16x8*)(src + 8);
            const __bf16* wq = wp + (kb + 1) * 64;
#pragma unroll
            for (int it = 0; it < 8; ++it)
                wN[it] = *(const bf16x8*)(wq + ((size_t)it << 17));
        }

        // ---- compute: 2 k-steps of 16x16x32, 4(m) x 4(n) per wave ----
#pragma unroll
        for (int ks = 0; ks < 2; ++ks) {
            bf16x8 af[4], bfr[4];
#pragma unroll
            for (int mi = 0; mi < 4; ++mi)
                af[mi] = *(bf16x8*)&Alds[(mi * 16 + r16) * LDA + ks * 32 + q * 8];
#pragma unroll
            for (int ni = 0; ni < 4; ++ni)
                bfr[ni] = *(bf16x8*)&Wlds[(wid * 64 + ni * 16 + r16) * LDA + ks * 32 + q * 8];
#pragma unroll
            for (int mi = 0; mi < 4; ++mi)
#pragma unroll
                for (int ni = 0; ni < 4; ++ni)
                    acc[mi][ni] = __builtin_amdgcn_mfma_f32_16x16x32_bf16(
                        af[mi], bfr[ni], acc[mi][ni], 0, 0, 0);
        }
        __syncthreads();
    }

    // ---- epilogue: C/D layout col=lane&15, row=(lane>>4)*4+reg ----
    float bv[4];
#pragma unroll
    for (int ni = 0; ni < 4; ++ni)
        bv[ni] = bias[wid * 64 + ni * 16 + r16];
#pragma unroll
    for (int mi = 0; mi < 4; ++mi) {
#pragma unroll
        for (int rr = 0; rr < 4; ++rr) {
            const int lt = q * 4 + rr;            // l within tile
            float* dst = out + (((size_t)(mi * Ldim + l0 + lt)) << 8) + wid * 64 + r16;
#pragma unroll
            for (int ni = 0; ni < 4; ++ni)
                dst[ni * 16] = acc[mi][ni][rr] + bv[ni];
        }
    }
}

// ---------------- fallback (no-ws path) ----------------
#define FTL 32
#define FBN 128
#define FLDA 72
__global__ __launch_bounds__(256)
void piconv_fallback(const float* __restrict__ x,
                     const int* __restrict__ idxT,
                     const float* __restrict__ mask,
                     const float* __restrict__ bias,
                     float* __restrict__ out)
{
    __shared__ __bf16 Alds[128 * FLDA];
    __shared__ __bf16 Wlds[FBN * FLDA];
    const int t  = threadIdx.x;
    const int l0 = blockIdx.x * FTL;
    const int n0 = blockIdx.y * FBN;
    const int lane = t & 63;
    const int wid  = t >> 6;
    const int wm   = wid >> 1;
    const int wn   = wid & 1;
    const int q    = lane >> 4;
    const int r16  = lane & 15;
    f32x4 acc[4][4] = {};
    const int am    = t >> 1;
    const int ahalf = t & 1;
    const int alt   = am & 31;
    const int abb   = am >> 5;
    const int al    = l0 + alt;
    const bool avalid = (al < Ldim);
    for (int kb = 0; kb < 64; ++kb) {
        {
            const int ksl = kb >> 2;
            const int i0  = ((kb & 3) << 6) + (ahalf << 5);
            const int idx = avalid ? idxT[al * Kdim + ksl] : 0;
            const float* src = x + (((size_t)(abb * Ldim + idx)) << 8) + i0;
#pragma unroll
            for (int j = 0; j < 4; ++j) {
                const float4 f0 = *(const float4*)(src + j * 8);
                const float4 f1 = *(const float4*)(src + j * 8 + 4);
                bf16x8 v;
                v[0] = (__bf16)f0.x; v[1] = (__bf16)f0.y; v[2] = (__bf16)f0.z; v[3] = (__bf16)f0.w;
                v[4] = (__bf16)f1.x; v[5] = (__bf16)f1.y; v[6] = (__bf16)f1.z; v[7] = (__bf16)f1.w;
                *(bf16x8*)&Alds[am * FLDA + (ahalf << 5) + j * 8] = v;
            }
        }
        {
#pragma unroll
            for (int it = 0; it < 4; ++it) {
                const int pair = t + it * 256;
                const int n    = pair & 127;
                const int g    = pair >> 7;
                const float* src = mask + (((size_t)(kb * 64 + g * 8)) << 8) + n0 + n;
                bf16x8 v;
#pragma unroll
                for (int j = 0; j < 8; ++j)
                    v[j] = (__bf16)src[(size_t)j << 8];
                *(bf16x8*)&Wlds[n * FLDA + g * 8] = v;
            }
        }
        __syncthreads();
#pragma unroll
        for (int ks = 0; ks < 2; ++ks) {
            bf16x8 af[4], bfr[4];
#pragma unroll
            for (int mi = 0; mi < 4; ++mi)
                af[mi] = *(bf16x8*)&Alds[(wm * 64 + mi * 16 + r16) * FLDA + ks * 32 + q * 8];
#pragma unroll
            for (int ni = 0; ni < 4; ++ni)
                bfr[ni] = *(bf16x8*)&Wlds[(wn * 64 + ni * 16 + r16) * FLDA + ks * 32 + q * 8];
#pragma unroll
            for (int mi = 0; mi < 4; ++mi)
#pragma unroll
                for (int ni = 0; ni < 4; ++ni)
                    acc[mi][ni] = __builtin_amdgcn_mfma_f32_16x16x32_bf16(
                        af[mi], bfr[ni], acc[mi][ni], 0, 0, 0);
        }
        __syncthreads();
    }
    float bv[4];
#pragma unroll
    for (int ni = 0; ni < 4; ++ni)
        bv[ni] = bias[n0 + wn * 64 + ni * 16 + r16];
#pragma unroll
    for (int mi = 0; mi < 4; ++mi) {
        const int mrow = wm * 64 + mi * 16 + q * 4;
#pragma unroll
        for (int rr = 0; rr < 4; ++rr) {
            const int m  = mrow + rr;
            const int lt = m & 31;
            const int bb = m >> 5;
            const int l  = l0 + lt;
            if (l < Ldim) {
                float* dst = out + (((size_t)(bb * Ldim + l)) << 8) + n0 + wn * 64 + r16;
#pragma unroll
                for (int ni = 0; ni < 4; ++ni)
                    dst[ni * 16] = acc[mi][ni][rr] + bv[ni];
            }
        }
    }
}

extern "C" void kernel_launch(void* const* d_in, const int* in_sizes, int n_in,
                              void* d_out, int out_size, void* d_ws, size_t ws_size,
                              hipStream_t stream) {
    const float* x    = (const float*)d_in[0];
    const int*   idx  = (const int*)d_in[1];
    const float* mask = (const float*)d_in[2];
    const float* bias = (const float*)d_in[3];
    float* out = (float*)d_out;

    const size_t xb_bytes = (size_t)Bdim * Ldim * Idim * 2;
    const size_t wt_bytes = (size_t)Kdim * Idim * Odim * 2;

    if (ws_size >= xb_bytes + wt_bytes) {
        __bf16* xb = (__bf16*)d_ws;
        __bf16* wt = (__bf16*)((char*)d_ws + xb_bytes);
        convert_x<<<(Bdim * Ldim * Idim) / (256 * 16), 256, 0, stream>>>(x, xb);
        convert_mask<<<dim3((Kdim * Idim) / 32, Odim / 32), 256, 0, stream>>>(mask, wt);
        piconv_gemm<<<Ldim / TL, 256, 0, stream>>>(xb, idx, wt, bias, out);
    } else {
        dim3 grid((Ldim + FTL - 1) / FTL, Odim / FBN, 1);
        piconv_fallback<<<grid, 256, 0, stream>>>(x, idx, mask, bias, out);
    }
}

// Round 5
// 187.848 us; speedup vs baseline: 3.2361x; 1.1664x over previous
//
#include <hip/hip_runtime.h>

// Problem: y[b,l,o] = sum_{k,i} x[b, idx[l,k], i] * mask[k,i,o] + bias[o]
// B=4, L=10000, K=16, I=256, O=256  => gathered GEMM M=40000, N=256, KK=4096
#define Bdim 4
#define Ldim 10000
#define Kdim 16
#define Idim 256
#define Odim 256

typedef __attribute__((ext_vector_type(8))) __bf16 bf16x8;
typedef __attribute__((ext_vector_type(4))) float f32x4;

// ---------------- fused pre-pass ----------------
// blocks [0,2500): convert x fp32->bf16 (4096 floats per block: 256 thr x 16)
// blocks [2500,3012): pack mask into B-fragment order Wpk[c][lane][8],
//                     c = kb*32 + wid*8 + ks*4 + ni
__global__ __launch_bounds__(256)
void prepack(const float* __restrict__ x, const float* __restrict__ mask,
             __bf16* __restrict__ xb, __bf16* __restrict__ wpk)
{
    const int b = blockIdx.x;
    if (b < 2500) {
        const size_t base = ((size_t)b * 256 + threadIdx.x) * 16;
#pragma unroll
        for (int j = 0; j < 2; ++j) {
            const float4 f0 = *(const float4*)(x + base + j * 8);
            const float4 f1 = *(const float4*)(x + base + j * 8 + 4);
            bf16x8 v;
            v[0] = (__bf16)f0.x; v[1] = (__bf16)f0.y; v[2] = (__bf16)f0.z; v[3] = (__bf16)f0.w;
            v[4] = (__bf16)f1.x; v[5] = (__bf16)f1.y; v[6] = (__bf16)f1.z; v[7] = (__bf16)f1.w;
            *(bf16x8*)(xb + base + j * 8) = v;
        }
    } else {
        const int tg = (b - 2500) * 256 + threadIdx.x;    // 0..131071
        const int c  = tg >> 6;                            // chunk 0..2047
        const int ln = tg & 63;
        const int ni  = c & 3;
        const int ks  = (c >> 2) & 1;
        const int wid = (c >> 3) & 3;
        const int kb  = c >> 5;
        const int n   = wid * 64 + ni * 16 + (ln & 15);
        const int kk0 = kb * 64 + ks * 32 + (ln >> 4) * 8;
        bf16x8 v;
#pragma unroll
        for (int j = 0; j < 8; ++j)
            v[j] = (__bf16)mask[(size_t)(kk0 + j) * Odim + n];
        *(bf16x8*)(wpk + (size_t)tg * 8) = v;
    }
}

// ---------------- main GEMM ----------------
#define TL 16          // l per block -> 625 blocks exact
#define BM 64          // = Bdim * TL
#define LDA 72         // LDS row stride in bf16 (64 + 8 pad)

__global__ __launch_bounds__(256, 3)
void piconv_gemm(const __bf16* __restrict__ xb,
                 const int* __restrict__ idxT,
                 const __bf16* __restrict__ wpk,
                 const float* __restrict__ bias,
                 float* __restrict__ out)
{
    __shared__ __bf16 Alds[2][BM * LDA];   // 2 x 9.2 KB
    __shared__ int    idx_lds[TL * Kdim];  // 1 KB

    const int t    = threadIdx.x;
    const int l0   = blockIdx.x * TL;
    const int lane = t & 63;
    const int wid  = t >> 6;               // n-quadrant: n in [wid*64, wid*64+64)
    const int q    = lane >> 4;
    const int r16  = lane & 15;

    idx_lds[t] = idxT[l0 * Kdim + t];      // 256 = TL*Kdim

    // A staging: 4 threads per row, 16 bf16 (32 B) each
    const int arow  = t >> 2;              // 0..63
    const int apart = t & 3;
    const int alt   = arow & 15;
    const int abb   = arow >> 4;
    const size_t abase = ((size_t)abb * Ldim) << 8;

    // W fragment base: + kb*16384 + (ks*4+ni)*512; 1024 B contiguous per wave-load
    const __bf16* wbase = wpk + ((size_t)(wid * 8) << 9) + lane * 8;

    f32x4  acc[4][4] = {};
    bf16x8 aN0, aN1, wA[8], wB[8];

    __syncthreads();                       // idx table ready

    // prologue: load kb=0 into regs
    {
        const int iv = idx_lds[alt * Kdim];
        const __bf16* s = xb + abase + (((size_t)iv) << 8) + apart * 16;
        aN0 = *(const bf16x8*)s;
        aN1 = *(const bf16x8*)(s + 8);
#pragma unroll
        for (int j = 0; j < 8; ++j)
            wA[j] = *(const bf16x8*)(wbase + j * 512);
    }

#define STEP(KB, BUF, WCUR, WNXT, PF)                                           \
    {                                                                           \
        *(bf16x8*)&Alds[BUF][arow * LDA + apart * 16]     = aN0;                \
        *(bf16x8*)&Alds[BUF][arow * LDA + apart * 16 + 8] = aN1;                \
        __syncthreads();                                                        \
        if (PF) {                                                               \
            const int kn = ((KB) + 1) >> 2;                                     \
            const int io = ((((KB) + 1) & 3) << 6) + apart * 16;                \
            const int iv = idx_lds[alt * Kdim + kn];                            \
            const __bf16* s = xb + abase + (((size_t)iv) << 8) + io;            \
            aN0 = *(const bf16x8*)s;                                            \
            aN1 = *(const bf16x8*)(s + 8);                                      \
            const __bf16* wq = wbase + ((size_t)((KB) + 1)) * 16384;            \
            _Pragma("unroll")                                                   \
            for (int j = 0; j < 8; ++j)                                         \
                WNXT[j] = *(const bf16x8*)(wq + j * 512);                       \
        }                                                                       \
        _Pragma("unroll")                                                       \
        for (int ks = 0; ks < 2; ++ks) {                                        \
            bf16x8 af[4];                                                       \
            _Pragma("unroll")                                                   \
            for (int mi = 0; mi < 4; ++mi)                                      \
                af[mi] = *(bf16x8*)&Alds[BUF][(mi * 16 + r16) * LDA + ks * 32 + q * 8]; \
            _Pragma("unroll")                                                   \
            for (int mi = 0; mi < 4; ++mi)                                      \
                _Pragma("unroll")                                               \
                for (int ni = 0; ni < 4; ++ni)                                  \
                    acc[mi][ni] = __builtin_amdgcn_mfma_f32_16x16x32_bf16(      \
                        af[mi], WCUR[ks * 4 + ni], acc[mi][ni], 0, 0, 0);       \
        }                                                                       \
    }

    for (int kb2 = 0; kb2 < 32; ++kb2) {
        STEP(2 * kb2,     0, wA, wB, true)
        STEP(2 * kb2 + 1, 1, wB, wA, (2 * kb2 + 1) < 63)
    }
#undef STEP

    // ---- epilogue: C/D layout col=lane&15, row=(lane>>4)*4+reg ----
    float bv[4];
#pragma unroll
    for (int ni = 0; ni < 4; ++ni)
        bv[ni] = bias[wid * 64 + ni * 16 + r16];
#pragma unroll
    for (int mi = 0; mi < 4; ++mi) {          // mi = batch index (BM=64 = 4b x 16l)
#pragma unroll
        for (int rr = 0; rr < 4; ++rr) {
            const int lt = q * 4 + rr;
            float* dst = out + (((size_t)(mi * Ldim + l0 + lt)) << 8) + wid * 64 + r16;
#pragma unroll
            for (int ni = 0; ni < 4; ++ni)
                dst[ni * 16] = acc[mi][ni][rr] + bv[ni];
        }
    }
}

// ---------------- fallback (no-ws path) ----------------
#define FTL 32
#define FBN 128
#define FLDA 72
__global__ __launch_bounds__(256)
void piconv_fallback(const float* __restrict__ x,
                     const int* __restrict__ idxT,
                     const float* __restrict__ mask,
                     const float* __restrict__ bias,
                     float* __restrict__ out)
{
    __shared__ __bf16 Alds[128 * FLDA];
    __shared__ __bf16 Wlds[FBN * FLDA];
    const int t  = threadIdx.x;
    const int l0 = blockIdx.x * FTL;
    const int n0 = blockIdx.y * FBN;
    const int lane = t & 63;
    const int wid  = t >> 6;
    const int wm   = wid >> 1;
    const int wn   = wid & 1;
    const int q    = lane >> 4;
    const int r16  = lane & 15;
    f32x4 acc[4][4] = {};
    const int am    = t >> 1;
    const int ahalf = t & 1;
    const int alt   = am & 31;
    const int abb   = am >> 5;
    const int al    = l0 + alt;
    const bool avalid = (al < Ldim);
    for (int kb = 0; kb < 64; ++kb) {
        {
            const int ksl = kb >> 2;
            const int i0  = ((kb & 3) << 6) + (ahalf << 5);
            const int idx = avalid ? idxT[al * Kdim + ksl] : 0;
            const float* src = x + (((size_t)(abb * Ldim + idx)) << 8) + i0;
#pragma unroll
            for (int j = 0; j < 4; ++j) {
                const float4 f0 = *(const float4*)(src + j * 8);
                const float4 f1 = *(const float4*)(src + j * 8 + 4);
                bf16x8 v;
                v[0] = (__bf16)f0.x; v[1] = (__bf16)f0.y; v[2] = (__bf16)f0.z; v[3] = (__bf16)f0.w;
                v[4] = (__bf16)f1.x; v[5] = (__bf16)f1.y; v[6] = (__bf16)f1.z; v[7] = (__bf16)f1.w;
                *(bf16x8*)&Alds[am * FLDA + (ahalf << 5) + j * 8] = v;
            }
        }
        {
#pragma unroll
            for (int it = 0; it < 4; ++it) {
                const int pair = t + it * 256;
                const int n    = pair & 127;
                const int g    = pair >> 7;
                const float* src = mask + (((size_t)(kb * 64 + g * 8)) << 8) + n0 + n;
                bf16x8 v;
#pragma unroll
                for (int j = 0; j < 8; ++j)
                    v[j] = (__bf16)src[(size_t)j << 8];
                *(bf16x8*)&Wlds[n * FLDA + g * 8] = v;
            }
        }
        __syncthreads();
#pragma unroll
        for (int ks = 0; ks < 2; ++ks) {
            bf16x8 af[4], bfr[4];
#pragma unroll
            for (int mi = 0; mi < 4; ++mi)
                af[mi] = *(bf16x8*)&Alds[(wm * 64 + mi * 16 + r16) * FLDA + ks * 32 + q * 8];
#pragma unroll
            for (int ni = 0; ni < 4; ++ni)
                bfr[ni] = *(bf16x8*)&Wlds[(wn * 64 + ni * 16 + r16) * FLDA + ks * 32 + q * 8];
#pragma unroll
            for (int mi = 0; mi < 4; ++mi)
#pragma unroll
                for (int ni = 0; ni < 4; ++ni)
                    acc[mi][ni] = __builtin_amdgcn_mfma_f32_16x16x32_bf16(
                        af[mi], bfr[ni], acc[mi][ni], 0, 0, 0);
        }
        __syncthreads();
    }
    float bv[4];
#pragma unroll
    for (int ni = 0; ni < 4; ++ni)
        bv[ni] = bias[n0 + wn * 64 + ni * 16 + r16];
#pragma unroll
    for (int mi = 0; mi < 4; ++mi) {
        const int mrow = wm * 64 + mi * 16 + q * 4;
#pragma unroll
        for (int rr = 0; rr < 4; ++rr) {
            const int m  = mrow + rr;
            const int lt = m & 31;
            const int bb = m >> 5;
            const int l  = l0 + lt;
            if (l < Ldim) {
                float* dst = out + (((size_t)(bb * Ldim + l)) << 8) + n0 + wn * 64 + r16;
#pragma unroll
                for (int ni = 0; ni < 4; ++ni)
                    dst[ni * 16] = acc[mi][ni][rr] + bv[ni];
            }
        }
    }
}

extern "C" void kernel_launch(void* const* d_in, const int* in_sizes, int n_in,
                              void* d_out, int out_size, void* d_ws, size_t ws_size,
                              hipStream_t stream) {
    const float* x    = (const float*)d_in[0];
    const int*   idx  = (const int*)d_in[1];
    const float* mask = (const float*)d_in[2];
    const float* bias = (const float*)d_in[3];
    float* out = (float*)d_out;

    const size_t xb_bytes = (size_t)Bdim * Ldim * Idim * 2;   // 20,480,000
    const size_t wp_bytes = (size_t)Kdim * Idim * Odim * 2;   //  2,097,152

    if (ws_size >= xb_bytes + wp_bytes) {
        __bf16* xb  = (__bf16*)d_ws;
        __bf16* wpk = (__bf16*)((char*)d_ws + xb_bytes);
        // 2500 x-convert blocks (2500*256*16 = 10,240,000 floats, exact) + 512 pack blocks
        prepack<<<2500 + 512, 256, 0, stream>>>(x, mask, xb, wpk);
        piconv_gemm<<<Ldim / TL, 256, 0, stream>>>(xb, idx, wpk, bias, out);
    } else {
        dim3 grid((Ldim + FTL - 1) / FTL, Odim / FBN, 1);
        piconv_fallback<<<grid, 256, 0, stream>>>(x, idx, mask, bias, out);
    }
}